// Round 4
// baseline (397.696 us; speedup 1.0000x reference)
//
#include <hip/hip_runtime.h>
#include <math.h>

#define D_MODEL 2048
#define NE      64
#define BM      128              // gemm tile: 128 tokens x 64 experts
#define KC      16               // k-chunk (floats)
#define KS      4                // split-K factor
#define KSEG    (D_MODEL / KS)   // 512
#define NCHK    (KSEG / KC)      // 32 chunks per K-segment
#define FB_KC   32
#define FB_NCH  (D_MODEL / FB_KC)

// async 16B global->LDS DMA (LDS dest = wave-uniform base + lane*16)
__device__ __forceinline__ void async_copy16(const float* g, float* l) {
    __builtin_amdgcn_global_load_lds(
        (const __attribute__((address_space(1))) unsigned int*)g,
        (__attribute__((address_space(3))) unsigned int*)l, 16, 0, 0);
}

__device__ __forceinline__ void loadW8(float4 dst[8], const float* wb, int kq) {
    #pragma unroll
    for (int j = 0; j < 8; ++j)
        dst[j] = *(const float4*)&wb[(size_t)j * D_MODEL + kq * 4];
}

__device__ __forceinline__ void fma128(float A[4][8], const float4 av[4],
                                       const float4 wr[8]) {
    #pragma unroll
    for (int i = 0; i < 4; ++i)
        #pragma unroll
        for (int j = 0; j < 8; ++j) {
            A[i][j] = fmaf(av[i].x, wr[j].x, A[i][j]);
            A[i][j] = fmaf(av[i].y, wr[j].y, A[i][j]);
            A[i][j] = fmaf(av[i].z, wr[j].z, A[i][j]);
            A[i][j] = fmaf(av[i].w, wr[j].w, A[i][j]);
        }
}

// one 16-k chunk: W software-pipelined in regs; stage(ch+2) injected at kq==3
// so the compiler's W-use waitcnts (vmcnt) leave the new DMA in flight
__device__ __forceinline__ void do_chunk(
    float A[4][8], const float* lbase, const float* wb,
    bool do_stage, const float* sg, float* sl0, float* sl1, int mq)
{
    float4 w0[8], w1[8];
    loadW8(w0, wb, 0);
    #pragma unroll
    for (int kq = 0; kq < 4; ++kq) {
        if (kq == 0) loadW8(w1, wb, 1);
        if (kq == 1) loadW8(w0, wb, 2);
        if (kq == 2) loadW8(w1, wb, 3);
        if (kq == 3 && do_stage) {
            async_copy16(sg, sl0);
            async_copy16(sg + 64 * D_MODEL, sl1);
        }
        float4 av[4];
        #pragma unroll
        for (int i = 0; i < 4; ++i)
            av[i] = *(const float4*)&lbase[(mq * 4 + i) * 16
                                           + (((kq ^ mq) & 3) << 2)];
        if (kq & 1) fma128(A, av, w1);
        else        fma128(A, av, w0);
    }
}

// ---------------- split-K GEMM: x[128 tok] x W[64 exp] over KSEG ------------
// A staged via global_load_lds (3-buffer, 2 chunks ahead, counted vmcnt);
// W never touches LDS (L1/L2-resident, each thread keeps 8 experts in regs).
// LDS layout row-major [128][16], quad-swizzled: row r, quad slot p holds
// source quad p ^ ((r>>2)&3)  (source pre-swizzled, read side XORs -> rule #21)
__global__ __launch_bounds__(256, 2) void router_gemm2(
    const float* __restrict__ x, const float* __restrict__ W,
    float* __restrict__ part, int ntiles)
{
    __shared__ __align__(16) float sX[3][BM * KC];   // 3 x 8KB

    const int t    = threadIdx.x;
    const int tile = blockIdx.x;
    const int ks   = blockIdx.y;
    const int m0   = tile * BM;
    const int k0   = ks * KSEG;
    const int nq   = t & 7;          // expert octet: e = nq*8 + j
    const int mq   = t >> 3;         // token quad:   m = mq*4 + i  (0..31)
    const int wv   = t >> 6;         // wave id

    // staging source (inverse-swizzled global address, LDS dest linear)
    const float* srcA = x + (size_t)(m0 + (t >> 2)) * D_MODEL + k0
                          + 4 * ((t & 3) ^ ((t >> 4) & 3));
    const float* Wbase = W + (size_t)(nq * 8) * D_MODEL + k0;

    float acc0[4][8] = {};           // even chunks (chain length 256, proven)
    float acc1[4][8] = {};           // odd chunks

    // prologue: stage chunks 0 and 1
    {
        async_copy16(srcA,                 &sX[0][wv * 256]);
        async_copy16(srcA + 64 * D_MODEL,  &sX[0][1024 + wv * 256]);
        async_copy16(srcA + KC,            &sX[1][wv * 256]);
        async_copy16(srcA + KC + 64 * D_MODEL, &sX[1][1024 + wv * 256]);
    }

    int bufc = 0;
    for (int ch = 0; ch < NCHK; ++ch) {
        if (ch + 1 < NCHK) { asm volatile("s_waitcnt vmcnt(2)" ::: "memory"); }
        else               { asm volatile("s_waitcnt vmcnt(0)" ::: "memory"); }
        __builtin_amdgcn_s_barrier();
        __builtin_amdgcn_sched_barrier(0);
        const int bufs = (bufc == 0) ? 2 : bufc - 1;     // (bufc+2)%3
        const bool st  = (ch + 2 < NCHK);
        const float* sg = srcA + (size_t)(ch + 2) * KC;
        float* sl0 = &sX[bufs][wv * 256];
        float* sl1 = &sX[bufs][1024 + wv * 256];
        if (ch & 1) do_chunk(acc1, &sX[bufc][0], Wbase + (ch << 4), st, sg, sl0, sl1, mq);
        else        do_chunk(acc0, &sX[bufc][0], Wbase + (ch << 4), st, sg, sl0, sl1, mq);
        bufc = (bufc == 2) ? 0 : bufc + 1;
    }

    float* dst = part + ((size_t)ks * ntiles + tile) * (BM * NE);
    #pragma unroll
    for (int i = 0; i < 4; ++i) {
        float4 lo, hi;
        lo.x = acc0[i][0] + acc1[i][0]; lo.y = acc0[i][1] + acc1[i][1];
        lo.z = acc0[i][2] + acc1[i][2]; lo.w = acc0[i][3] + acc1[i][3];
        hi.x = acc0[i][4] + acc1[i][4]; hi.y = acc0[i][5] + acc1[i][5];
        hi.z = acc0[i][6] + acc1[i][6]; hi.w = acc0[i][7] + acc1[i][7];
        *(float4*)&dst[(mq * 4 + i) * NE + nq * 8]     = lo;
        *(float4*)&dst[(mq * 4 + i) * NE + nq * 8 + 4] = hi;
    }
}

// ---------------- reduce partials + fused stats (64 tokens/block) -----------
__global__ __launch_bounds__(256) void router_stats2(
    const float* __restrict__ part, float* __restrict__ out,
    float* __restrict__ ws_prob, float* __restrict__ ws_z,
    int* __restrict__ ws_cnt, int Ntok, int ntiles_g)
{
    __shared__ float sL[64][NE + 1];
    __shared__ float red4[64][4];
    __shared__ int   arg4[64][4];
    __shared__ float smax[64], sinv[64];
    __shared__ float spart[4][NE];
    __shared__ int   hist[NE];

    const int t = threadIdx.x, b = blockIdx.x, m0 = b * 64;
    const size_t ksstride = (size_t)ntiles_g * (BM * NE);
    const float* base = part + (size_t)(b >> 1) * (BM * NE)
                             + (size_t)(b & 1) * (64 * NE);

    #pragma unroll
    for (int r = 0; r < 4; ++r) {                    // sum 4 K-partials
        const int q = r * 256 + t;
        const float* p0 = base + (size_t)q * 4;
        float4 v0 = *(const float4*)(p0);
        float4 v1 = *(const float4*)(p0 + ksstride);
        float4 v2 = *(const float4*)(p0 + 2 * ksstride);
        float4 v3 = *(const float4*)(p0 + 3 * ksstride);
        const int row = q >> 4, col = (q & 15) << 2;
        sL[row][col]     = ((v0.x + v1.x) + v2.x) + v3.x;
        sL[row][col + 1] = ((v0.y + v1.y) + v2.y) + v3.y;
        sL[row][col + 2] = ((v0.z + v1.z) + v2.z) + v3.z;
        sL[row][col + 3] = ((v0.w + v1.w) + v2.w) + v3.w;
    }
    if (t < NE) hist[t] = 0;
    __syncthreads();

    {   // per-quarter argmax (4 threads per token)
        const int m = t >> 2, qr = t & 3;
        float mx = -3.4e38f; int ag = 0;
        #pragma unroll
        for (int k = 0; k < 16; ++k) {
            const int e = qr * 16 + k;
            float v = sL[m][e];
            if (v > mx) { mx = v; ag = e; }
        }
        red4[m][qr] = mx; arg4[m][qr] = ag;
    }
    __syncthreads();
    if (t < 64) {                                    // combine: first-max kept
        const int m = t;
        float mx = red4[m][0]; int ag = arg4[m][0];
        #pragma unroll
        for (int qr = 1; qr < 4; ++qr)
            if (red4[m][qr] > mx) { mx = red4[m][qr]; ag = arg4[m][qr]; }
        smax[m] = mx;
        out[m0 + m] = (float)ag;                     // expert_index
        atomicAdd(&hist[ag], 1);
    }
    __syncthreads();
    {   // per-quarter expsum
        const int m = t >> 2, qr = t & 3;
        const float mx = smax[m];
        float s = 0.f;
        #pragma unroll
        for (int k = 0; k < 16; ++k) s += expf(sL[m][qr * 16 + k] - mx);
        red4[m][qr] = s;
    }
    __syncthreads();
    if (t < 64) {
        const int m = t;
        float s = ((red4[m][0] + red4[m][1]) + red4[m][2]) + red4[m][3];
        float inv = 1.f / s;
        sinv[m] = inv;
        out[Ntok + m0 + m] = inv;                    // expert_prob
        float lse = smax[m] + logf(s);
        float z = lse * lse;
        #pragma unroll
        for (int off = 32; off > 0; off >>= 1) z += __shfl_down(z, off, 64);
        if (t == 0) ws_z[b] = z;
    }
    __syncthreads();
    {   // probsum: wave mg covers 16 tokens, lane = expert
        const int e = t & 63, mg = t >> 6;
        float pa = 0.f;
        #pragma unroll
        for (int k = 0; k < 16; ++k) {
            const int m = mg * 16 + k;
            pa += expf(sL[m][e] - smax[m]) * sinv[m];
        }
        spart[mg][e] = pa;
    }
    __syncthreads();
    if (t < NE) {
        ws_prob[b * NE + t] = ((spart[0][t] + spart[1][t]) + spart[2][t]) + spart[3][t];
        ws_cnt[b * NE + t]  = hist[t];
    }
}

__global__ __launch_bounds__(64) void router_final_kernel(
    const float* __restrict__ ws_prob, const float* __restrict__ ws_z,
    const int* __restrict__ ws_cnt, float* __restrict__ out,
    int Ntok, int nblocks)
{
    const int e = threadIdx.x;
    float ps = 0.f; int c = 0;
    for (int blk = 0; blk < nblocks; ++blk) {        // fixed order: deterministic
        ps += ws_prob[blk * NE + e];
        c  += ws_cnt[blk * NE + e];
    }
    float z = 0.f;
    for (int blk = e; blk < nblocks; blk += 64) z += ws_z[blk];
    #pragma unroll
    for (int off = 32; off > 0; off >>= 1) z += __shfl_down(z, off, 64);

    float fN = (float)Ntok;
    float fp = ((float)c / fN) * (ps / fN);
    #pragma unroll
    for (int off = 32; off > 0; off >>= 1) fp += __shfl_down(fp, off, 64);

    out[2 * Ntok + e] = (float)c;
    if (e == 0) {
        int cap = (Ntok + NE - 1) / NE;
        if (cap < 4) cap = 4;
        float aux = 0.01f * (float)NE * fp + 1e-3f * (z / fN);
        out[2 * Ntok + NE]     = (float)cap;
        out[2 * Ntok + NE + 1] = aux;
    }
}

// ---------------- fallback (round-1 proven fused path) ----------------------
__global__ __launch_bounds__(256) void router_main_fb(
    const float* __restrict__ x, const float* __restrict__ W,
    float* __restrict__ out, float* __restrict__ ws_prob,
    float* __restrict__ ws_z, int* __restrict__ ws_cnt, int Ntok)
{
    __shared__ __align__(16) float sX[FB_KC][68];
    __shared__ __align__(16) float sW[FB_KC][68];
    __shared__ float sL[64][65];
    __shared__ float smax[64], sinv[64];
    __shared__ float spart[4][NE];
    __shared__ int   hist[NE];

    const int t = threadIdx.x, b = blockIdx.x, m0 = b * 64;
    const int mq = t & 15, nq = t >> 4;
    const int r1 = t >> 3, r2 = r1 + 32, c1 = (t & 7) << 2;
    const float* xp1 = x + (size_t)(m0 + r1) * D_MODEL + c1;
    const float* xp2 = x + (size_t)(m0 + r2) * D_MODEL + c1;
    const float* wp1 = W + (size_t)r1 * D_MODEL + c1;
    const float* wp2 = W + (size_t)r2 * D_MODEL + c1;
    float4 ax1 = *(const float4*)xp1, ax2 = *(const float4*)xp2;
    float4 aw1 = *(const float4*)wp1, aw2 = *(const float4*)wp2;
    float a1[4][4] = {}, a2[4][4] = {};
    for (int ch = 0; ch < FB_NCH; ++ch) {
        __syncthreads();
        sX[c1+0][r1] = ax1.x; sX[c1+1][r1] = ax1.y; sX[c1+2][r1] = ax1.z; sX[c1+3][r1] = ax1.w;
        sX[c1+0][r2] = ax2.x; sX[c1+1][r2] = ax2.y; sX[c1+2][r2] = ax2.z; sX[c1+3][r2] = ax2.w;
        sW[c1+0][r1] = aw1.x; sW[c1+1][r1] = aw1.y; sW[c1+2][r1] = aw1.z; sW[c1+3][r1] = aw1.w;
        sW[c1+0][r2] = aw2.x; sW[c1+1][r2] = aw2.y; sW[c1+2][r2] = aw2.z; sW[c1+3][r2] = aw2.w;
        __syncthreads();
        if (ch + 1 < FB_NCH) {
            xp1 += FB_KC; xp2 += FB_KC; wp1 += FB_KC; wp2 += FB_KC;
            ax1 = *(const float4*)xp1; ax2 = *(const float4*)xp2;
            aw1 = *(const float4*)wp1; aw2 = *(const float4*)wp2;
        }
        #pragma unroll
        for (int k = 0; k < FB_KC; ++k) {
            float4 xa = *(const float4*)&sX[k][mq << 2];
            float4 wb = *(const float4*)&sW[k][nq << 2];
            float (*A)[4] = (k < FB_KC / 2) ? a1 : a2;
            A[0][0] = fmaf(xa.x, wb.x, A[0][0]); A[0][1] = fmaf(xa.x, wb.y, A[0][1]);
            A[0][2] = fmaf(xa.x, wb.z, A[0][2]); A[0][3] = fmaf(xa.x, wb.w, A[0][3]);
            A[1][0] = fmaf(xa.y, wb.x, A[1][0]); A[1][1] = fmaf(xa.y, wb.y, A[1][1]);
            A[1][2] = fmaf(xa.y, wb.z, A[1][2]); A[1][3] = fmaf(xa.y, wb.w, A[1][3]);
            A[2][0] = fmaf(xa.z, wb.x, A[2][0]); A[2][1] = fmaf(xa.z, wb.y, A[2][1]);
            A[2][2] = fmaf(xa.z, wb.z, A[2][2]); A[2][3] = fmaf(xa.z, wb.w, A[2][3]);
            A[3][0] = fmaf(xa.w, wb.x, A[3][0]); A[3][1] = fmaf(xa.w, wb.y, A[3][1]);
            A[3][2] = fmaf(xa.w, wb.z, A[3][2]); A[3][3] = fmaf(xa.w, wb.w, A[3][3]);
        }
    }
    #pragma unroll
    for (int i = 0; i < 4; ++i)
        #pragma unroll
        for (int j = 0; j < 4; ++j)
            sL[(mq << 2) + i][(nq << 2) + j] = a1[i][j] + a2[i][j];
    if (t < NE) hist[t] = 0;
    __syncthreads();
    if (t < 64) {
        const int m = t;
        float mx = sL[m][0]; int arg = 0;
        for (int e = 1; e < NE; ++e) { float v = sL[m][e]; if (v > mx) { mx = v; arg = e; } }
        float s = 0.f;
        for (int e = 0; e < NE; ++e) s += expf(sL[m][e] - mx);
        float inv = 1.f / s;
        out[m0 + m] = (float)arg; out[Ntok + m0 + m] = inv;
        smax[m] = mx; sinv[m] = inv;
        atomicAdd(&hist[arg], 1);
        float lse = mx + logf(s); float z = lse * lse;
        for (int off = 32; off > 0; off >>= 1) z += __shfl_down(z, off, 64);
        if (t == 0) ws_z[b] = z;
    }
    __syncthreads();
    {
        const int e = t & 63, mg = t >> 6;
        float pa = 0.f;
        for (int m = mg * 16; m < mg * 16 + 16; ++m) pa += expf(sL[m][e] - smax[m]) * sinv[m];
        spart[mg][e] = pa;
    }
    __syncthreads();
    if (t < NE) {
        ws_prob[b * NE + t] = spart[0][t] + spart[1][t] + spart[2][t] + spart[3][t];
        ws_cnt[b * NE + t]  = hist[t];
    }
}

extern "C" void kernel_launch(void* const* d_in, const int* in_sizes, int n_in,
                              void* d_out, int out_size, void* d_ws, size_t ws_size,
                              hipStream_t stream)
{
    const float* x = (const float*)d_in[0];
    const float* W = (const float*)d_in[1];
    float* out = (float*)d_out;

    const int Ntok = in_sizes[0] / D_MODEL;          // 16384

    const int ntiles_g = Ntok / BM;                  // 128
    const int nstat    = Ntok / 64;                  // 256
    const size_t part_elems = (size_t)KS * ntiles_g * BM * NE;   // 4.19M floats
    const size_t need = (part_elems + (size_t)nstat * NE + nstat) * 4
                      + (size_t)nstat * NE * 4 + 1024;

    if ((Ntok % BM) == 0 && ws_size >= need) {
        float* ws_part = (float*)d_ws;
        float* ws_prob = ws_part + part_elems;
        float* ws_z    = ws_prob + (size_t)nstat * NE;
        int*   ws_cnt  = (int*)(ws_z + nstat);

        dim3 grid(ntiles_g, KS);
        router_gemm2<<<grid, 256, 0, stream>>>(x, W, ws_part, ntiles_g);
        router_stats2<<<nstat, 256, 0, stream>>>(ws_part, out, ws_prob, ws_z, ws_cnt, Ntok, ntiles_g);
        router_final_kernel<<<1, 64, 0, stream>>>(ws_prob, ws_z, ws_cnt, out, Ntok, nstat);
    } else {
        const int nb = Ntok / 64;
        float* ws_prob = (float*)d_ws;
        float* ws_z    = ws_prob + (size_t)nb * NE;
        int*   ws_cnt  = (int*)(ws_z + nb);
        router_main_fb<<<nb, 256, 0, stream>>>(x, W, out, ws_prob, ws_z, ws_cnt, Ntok);
        router_final_kernel<<<1, 64, 0, stream>>>(ws_prob, ws_z, ws_cnt, out, Ntok, nb);
    }
}

// Round 5
// 388.269 us; speedup vs baseline: 1.0243x; 1.0243x over previous
//
#include <hip/hip_runtime.h>
#include <math.h>

#define D_MODEL 2048
#define NE      64
#define BM      128              // gemm tile: 128 tokens x 64 experts
#define KC      16               // k-chunk (floats)
#define KS      8                // split-K factor
#define KSEG    (D_MODEL / KS)   // 256  (acc chain length 256 = round-2 proven)
#define NCHK    (KSEG / KC)      // 16 chunks per K-segment
#define FB_KC   32
#define FB_NCH  (D_MODEL / FB_KC)

// async 16B global->LDS DMA (LDS dest = wave-uniform base + lane*16)
__device__ __forceinline__ void async_copy16(const float* g, float* l) {
    __builtin_amdgcn_global_load_lds(
        (const __attribute__((address_space(1))) unsigned int*)g,
        (__attribute__((address_space(3))) unsigned int*)l, 16, 0, 0);
}

__device__ __forceinline__ void loadW8(float4 dst[8], const float* wb, int kq) {
    #pragma unroll
    for (int j = 0; j < 8; ++j)
        dst[j] = *(const float4*)&wb[(size_t)j * D_MODEL + kq * 4];
}

__device__ __forceinline__ void fma128(float A[4][8], const float4 av[4],
                                       const float4 wr[8]) {
    #pragma unroll
    for (int i = 0; i < 4; ++i)
        #pragma unroll
        for (int j = 0; j < 8; ++j) {
            A[i][j] = fmaf(av[i].x, wr[j].x, A[i][j]);
            A[i][j] = fmaf(av[i].y, wr[j].y, A[i][j]);
            A[i][j] = fmaf(av[i].z, wr[j].z, A[i][j]);
            A[i][j] = fmaf(av[i].w, wr[j].w, A[i][j]);
        }
}

// one 16-k chunk. W loaded JIT per k-quad (single w[8] buffer, 32 VGPR —
// round-4's w0/w1 ping-pong + dual acc spilled to scratch: 350MB writes).
// stage(ch+2) DMA injected at kq==3; the compiler's w-use vmcnt waits leave
// the 2 newest VMEM ops (the DMAs) in flight.
__device__ __forceinline__ void do_chunk(
    float A[4][8], const float* lbase, const float* wb,
    bool do_stage, const float* sg, float* sl0, float* sl1, int mq)
{
    #pragma unroll
    for (int kq = 0; kq < 4; ++kq) {
        float4 w[8];
        loadW8(w, wb, kq);
        if (kq == 3 && do_stage) {
            async_copy16(sg, sl0);
            async_copy16(sg + 64 * D_MODEL, sl1);
        }
        float4 av[4];
        #pragma unroll
        for (int i = 0; i < 4; ++i)
            av[i] = *(const float4*)&lbase[(mq * 4 + i) * 16
                                           + (((kq ^ mq) & 3) << 2)];
        fma128(A, av, w);
    }
}

// ---------------- split-K GEMM: x[128 tok] x W[64 exp] over KSEG ------------
// A staged via global_load_lds (3-buffer, 2 chunks ahead, counted vmcnt);
// W never touches LDS. LDS [128][16] quad-swizzled (source pre-swizzled,
// read XORs: rule #21) -> 2-way conflicts only (free; round-4 measured 0).
__global__ __launch_bounds__(256, 4) void router_gemm2(
    const float* __restrict__ x, const float* __restrict__ W,
    float* __restrict__ part, int ntiles)
{
    __shared__ __align__(16) float sX[3][BM * KC];   // 3 x 8KB

    const int t    = threadIdx.x;
    const int tile = blockIdx.x;
    const int ks   = blockIdx.y;
    const int m0   = tile * BM;
    const int k0   = ks * KSEG;
    const int nq   = t & 7;          // expert octet: e = nq*8 + j
    const int mq   = t >> 3;         // token quad:   m = mq*4 + i  (0..31)
    const int wv   = t >> 6;         // wave id

    // staging source (inverse-swizzled global address, LDS dest linear)
    const float* srcA = x + (size_t)(m0 + (t >> 2)) * D_MODEL + k0
                          + 4 * ((t & 3) ^ ((t >> 4) & 3));
    const float* Wbase = W + (size_t)(nq * 8) * D_MODEL + k0;

    float acc[4][8] = {};            // single chain (length 256, proven exact)

    // prologue: stage chunks 0 and 1
    async_copy16(srcA,                     &sX[0][wv * 256]);
    async_copy16(srcA + 64 * D_MODEL,      &sX[0][1024 + wv * 256]);
    async_copy16(srcA + KC,                &sX[1][wv * 256]);
    async_copy16(srcA + KC + 64 * D_MODEL, &sX[1][1024 + wv * 256]);

    int bufc = 0;
    for (int ch = 0; ch < NCHK; ++ch) {
        if (ch + 1 < NCHK) { asm volatile("s_waitcnt vmcnt(2)" ::: "memory"); }
        else               { asm volatile("s_waitcnt vmcnt(0)" ::: "memory"); }
        __builtin_amdgcn_s_barrier();
        __builtin_amdgcn_sched_barrier(0);
        const int bufs = (bufc == 0) ? 2 : bufc - 1;     // (bufc+2)%3
        const bool st  = (ch + 2 < NCHK);
        const float* sg = srcA + (size_t)(ch + 2) * KC;
        do_chunk(acc, &sX[bufc][0], Wbase + (ch << 4), st, sg,
                 &sX[bufs][wv * 256], &sX[bufs][1024 + wv * 256], mq);
        bufc = (bufc == 2) ? 0 : bufc + 1;
    }

    float* dst = part + ((size_t)ks * ntiles + tile) * (BM * NE);
    #pragma unroll
    for (int i = 0; i < 4; ++i) {
        float4 lo, hi;
        lo.x = acc[i][0]; lo.y = acc[i][1]; lo.z = acc[i][2]; lo.w = acc[i][3];
        hi.x = acc[i][4]; hi.y = acc[i][5]; hi.z = acc[i][6]; hi.w = acc[i][7];
        *(float4*)&dst[(mq * 4 + i) * NE + nq * 8]     = lo;
        *(float4*)&dst[(mq * 4 + i) * NE + nq * 8 + 4] = hi;
    }
}

// ---------------- reduce 8 partials + fused stats (64 tokens/block) ---------
__global__ __launch_bounds__(256) void router_stats2(
    const float* __restrict__ part, float* __restrict__ out,
    float* __restrict__ ws_prob, float* __restrict__ ws_z,
    int* __restrict__ ws_cnt, int Ntok, int ntiles_g)
{
    __shared__ float sL[64][NE + 1];
    __shared__ float red4[64][4];
    __shared__ int   arg4[64][4];
    __shared__ float smax[64], sinv[64];
    __shared__ float spart[4][NE];
    __shared__ int   hist[NE];

    const int t = threadIdx.x, b = blockIdx.x, m0 = b * 64;
    const size_t ksstride = (size_t)ntiles_g * (BM * NE);
    const float* base = part + (size_t)(b >> 1) * (BM * NE)
                             + (size_t)(b & 1) * (64 * NE);

    #pragma unroll
    for (int r = 0; r < 4; ++r) {                    // sum 8 K-partials
        const int q = r * 256 + t;
        const float* p0 = base + (size_t)q * 4;
        float s0 = 0.f, s1 = 0.f, s2 = 0.f, s3 = 0.f;
        float t0 = 0.f, t1 = 0.f, t2 = 0.f, t3 = 0.f;
        #pragma unroll
        for (int j = 0; j < 8; j += 2) {             // pairwise-ish, fixed order
            float4 va = *(const float4*)(p0 + (size_t)j * ksstride);
            float4 vb = *(const float4*)(p0 + (size_t)(j + 1) * ksstride);
            s0 += va.x + vb.x; s1 += va.y + vb.y;
            s2 += va.z + vb.z; s3 += va.w + vb.w;
            (void)t0; (void)t1; (void)t2; (void)t3;
        }
        const int row = q >> 4, col = (q & 15) << 2;
        sL[row][col]     = s0; sL[row][col + 1] = s1;
        sL[row][col + 2] = s2; sL[row][col + 3] = s3;
    }
    if (t < NE) hist[t] = 0;
    __syncthreads();

    {   // per-quarter argmax (4 threads per token)
        const int m = t >> 2, qr = t & 3;
        float mx = -3.4e38f; int ag = 0;
        #pragma unroll
        for (int k = 0; k < 16; ++k) {
            const int e = qr * 16 + k;
            float v = sL[m][e];
            if (v > mx) { mx = v; ag = e; }
        }
        red4[m][qr] = mx; arg4[m][qr] = ag;
    }
    __syncthreads();
    if (t < 64) {                                    // combine: first-max kept
        const int m = t;
        float mx = red4[m][0]; int ag = arg4[m][0];
        #pragma unroll
        for (int qr = 1; qr < 4; ++qr)
            if (red4[m][qr] > mx) { mx = red4[m][qr]; ag = arg4[m][qr]; }
        smax[m] = mx;
        out[m0 + m] = (float)ag;                     // expert_index
        atomicAdd(&hist[ag], 1);
    }
    __syncthreads();
    {   // per-quarter expsum
        const int m = t >> 2, qr = t & 3;
        const float mx = smax[m];
        float s = 0.f;
        #pragma unroll
        for (int k = 0; k < 16; ++k) s += expf(sL[m][qr * 16 + k] - mx);
        red4[m][qr] = s;
    }
    __syncthreads();
    if (t < 64) {
        const int m = t;
        float s = ((red4[m][0] + red4[m][1]) + red4[m][2]) + red4[m][3];
        float inv = 1.f / s;
        sinv[m] = inv;
        out[Ntok + m0 + m] = inv;                    // expert_prob
        float lse = smax[m] + logf(s);
        float z = lse * lse;
        #pragma unroll
        for (int off = 32; off > 0; off >>= 1) z += __shfl_down(z, off, 64);
        if (t == 0) ws_z[b] = z;
    }
    __syncthreads();
    {   // probsum: wave mg covers 16 tokens, lane = expert
        const int e = t & 63, mg = t >> 6;
        float pa = 0.f;
        #pragma unroll
        for (int k = 0; k < 16; ++k) {
            const int m = mg * 16 + k;
            pa += expf(sL[m][e] - smax[m]) * sinv[m];
        }
        spart[mg][e] = pa;
    }
    __syncthreads();
    if (t < NE) {
        ws_prob[b * NE + t] = ((spart[0][t] + spart[1][t]) + spart[2][t]) + spart[3][t];
        ws_cnt[b * NE + t]  = hist[t];
    }
}

__global__ __launch_bounds__(64) void router_final_kernel(
    const float* __restrict__ ws_prob, const float* __restrict__ ws_z,
    const int* __restrict__ ws_cnt, float* __restrict__ out,
    int Ntok, int nblocks)
{
    const int e = threadIdx.x;
    float ps = 0.f; int c = 0;
    for (int blk = 0; blk < nblocks; ++blk) {        // fixed order: deterministic
        ps += ws_prob[blk * NE + e];
        c  += ws_cnt[blk * NE + e];
    }
    float z = 0.f;
    for (int blk = e; blk < nblocks; blk += 64) z += ws_z[blk];
    #pragma unroll
    for (int off = 32; off > 0; off >>= 1) z += __shfl_down(z, off, 64);

    float fN = (float)Ntok;
    float fp = ((float)c / fN) * (ps / fN);
    #pragma unroll
    for (int off = 32; off > 0; off >>= 1) fp += __shfl_down(fp, off, 64);

    out[2 * Ntok + e] = (float)c;
    if (e == 0) {
        int cap = (Ntok + NE - 1) / NE;
        if (cap < 4) cap = 4;
        float aux = 0.01f * (float)NE * fp + 1e-3f * (z / fN);
        out[2 * Ntok + NE]     = (float)cap;
        out[2 * Ntok + NE + 1] = aux;
    }
}

// ---------------- fallback (round-1 proven fused path) ----------------------
__global__ __launch_bounds__(256) void router_main_fb(
    const float* __restrict__ x, const float* __restrict__ W,
    float* __restrict__ out, float* __restrict__ ws_prob,
    float* __restrict__ ws_z, int* __restrict__ ws_cnt, int Ntok)
{
    __shared__ __align__(16) float sX[FB_KC][68];
    __shared__ __align__(16) float sW[FB_KC][68];
    __shared__ float sL[64][65];
    __shared__ float smax[64], sinv[64];
    __shared__ float spart[4][NE];
    __shared__ int   hist[NE];

    const int t = threadIdx.x, b = blockIdx.x, m0 = b * 64;
    const int mq = t & 15, nq = t >> 4;
    const int r1 = t >> 3, r2 = r1 + 32, c1 = (t & 7) << 2;
    const float* xp1 = x + (size_t)(m0 + r1) * D_MODEL + c1;
    const float* xp2 = x + (size_t)(m0 + r2) * D_MODEL + c1;
    const float* wp1 = W + (size_t)r1 * D_MODEL + c1;
    const float* wp2 = W + (size_t)r2 * D_MODEL + c1;
    float4 ax1 = *(const float4*)xp1, ax2 = *(const float4*)xp2;
    float4 aw1 = *(const float4*)wp1, aw2 = *(const float4*)wp2;
    float a1[4][4] = {}, a2[4][4] = {};
    for (int ch = 0; ch < FB_NCH; ++ch) {
        __syncthreads();
        sX[c1+0][r1] = ax1.x; sX[c1+1][r1] = ax1.y; sX[c1+2][r1] = ax1.z; sX[c1+3][r1] = ax1.w;
        sX[c1+0][r2] = ax2.x; sX[c1+1][r2] = ax2.y; sX[c1+2][r2] = ax2.z; sX[c1+3][r2] = ax2.w;
        sW[c1+0][r1] = aw1.x; sW[c1+1][r1] = aw1.y; sW[c1+2][r1] = aw1.z; sW[c1+3][r1] = aw1.w;
        sW[c1+0][r2] = aw2.x; sW[c1+1][r2] = aw2.y; sW[c1+2][r2] = aw2.z; sW[c1+3][r2] = aw2.w;
        __syncthreads();
        if (ch + 1 < FB_NCH) {
            xp1 += FB_KC; xp2 += FB_KC; wp1 += FB_KC; wp2 += FB_KC;
            ax1 = *(const float4*)xp1; ax2 = *(const float4*)xp2;
            aw1 = *(const float4*)wp1; aw2 = *(const float4*)wp2;
        }
        #pragma unroll
        for (int k = 0; k < FB_KC; ++k) {
            float4 xa = *(const float4*)&sX[k][mq << 2];
            float4 wb = *(const float4*)&sW[k][nq << 2];
            float (*A)[4] = (k < FB_KC / 2) ? a1 : a2;
            A[0][0] = fmaf(xa.x, wb.x, A[0][0]); A[0][1] = fmaf(xa.x, wb.y, A[0][1]);
            A[0][2] = fmaf(xa.x, wb.z, A[0][2]); A[0][3] = fmaf(xa.x, wb.w, A[0][3]);
            A[1][0] = fmaf(xa.y, wb.x, A[1][0]); A[1][1] = fmaf(xa.y, wb.y, A[1][1]);
            A[1][2] = fmaf(xa.y, wb.z, A[1][2]); A[1][3] = fmaf(xa.y, wb.w, A[1][3]);
            A[2][0] = fmaf(xa.z, wb.x, A[2][0]); A[2][1] = fmaf(xa.z, wb.y, A[2][1]);
            A[2][2] = fmaf(xa.z, wb.z, A[2][2]); A[2][3] = fmaf(xa.z, wb.w, A[2][3]);
            A[3][0] = fmaf(xa.w, wb.x, A[3][0]); A[3][1] = fmaf(xa.w, wb.y, A[3][1]);
            A[3][2] = fmaf(xa.w, wb.z, A[3][2]); A[3][3] = fmaf(xa.w, wb.w, A[3][3]);
        }
    }
    #pragma unroll
    for (int i = 0; i < 4; ++i)
        #pragma unroll
        for (int j = 0; j < 4; ++j)
            sL[(mq << 2) + i][(nq << 2) + j] = a1[i][j] + a2[i][j];
    if (t < NE) hist[t] = 0;
    __syncthreads();
    if (t < 64) {
        const int m = t;
        float mx = sL[m][0]; int arg = 0;
        for (int e = 1; e < NE; ++e) { float v = sL[m][e]; if (v > mx) { mx = v; arg = e; } }
        float s = 0.f;
        for (int e = 0; e < NE; ++e) s += expf(sL[m][e] - mx);
        float inv = 1.f / s;
        out[m0 + m] = (float)arg; out[Ntok + m0 + m] = inv;
        smax[m] = mx; sinv[m] = inv;
        atomicAdd(&hist[arg], 1);
        float lse = mx + logf(s); float z = lse * lse;
        for (int off = 32; off > 0; off >>= 1) z += __shfl_down(z, off, 64);
        if (t == 0) ws_z[b] = z;
    }
    __syncthreads();
    {
        const int e = t & 63, mg = t >> 6;
        float pa = 0.f;
        for (int m = mg * 16; m < mg * 16 + 16; ++m) pa += expf(sL[m][e] - smax[m]) * sinv[m];
        spart[mg][e] = pa;
    }
    __syncthreads();
    if (t < NE) {
        ws_prob[b * NE + t] = spart[0][t] + spart[1][t] + spart[2][t] + spart[3][t];
        ws_cnt[b * NE + t]  = hist[t];
    }
}

extern "C" void kernel_launch(void* const* d_in, const int* in_sizes, int n_in,
                              void* d_out, int out_size, void* d_ws, size_t ws_size,
                              hipStream_t stream)
{
    const float* x = (const float*)d_in[0];
    const float* W = (const float*)d_in[1];
    float* out = (float*)d_out;

    const int Ntok = in_sizes[0] / D_MODEL;          // 16384

    const int ntiles_g = Ntok / BM;                  // 128
    const int nstat    = Ntok / 64;                  // 256
    const size_t part_elems = (size_t)KS * ntiles_g * BM * NE;   // 8.39M floats
    const size_t need = (part_elems + (size_t)nstat * NE + nstat) * 4
                      + (size_t)nstat * NE * 4 + 1024;

    if ((Ntok % BM) == 0 && ws_size >= need) {
        float* ws_part = (float*)d_ws;
        float* ws_prob = ws_part + part_elems;
        float* ws_z    = ws_prob + (size_t)nstat * NE;
        int*   ws_cnt  = (int*)(ws_z + nstat);

        dim3 grid(ntiles_g, KS);
        router_gemm2<<<grid, 256, 0, stream>>>(x, W, ws_part, ntiles_g);
        router_stats2<<<nstat, 256, 0, stream>>>(ws_part, out, ws_prob, ws_z, ws_cnt, Ntok, ntiles_g);
        router_final_kernel<<<1, 64, 0, stream>>>(ws_prob, ws_z, ws_cnt, out, Ntok, nstat);
    } else {
        const int nb = Ntok / 64;
        float* ws_prob = (float*)d_ws;
        float* ws_z    = ws_prob + (size_t)nb * NE;
        int*   ws_cnt  = (int*)(ws_z + nb);
        router_main_fb<<<nb, 256, 0, stream>>>(x, W, out, ws_prob, ws_z, ws_cnt, Ntok);
        router_final_kernel<<<1, 64, 0, stream>>>(ws_prob, ws_z, ws_cnt, out, Ntok, nb);
    }
}

// Round 6
// 146.184 us; speedup vs baseline: 2.7205x; 2.6560x over previous
//
#include <hip/hip_runtime.h>
#include <math.h>

#define D_MODEL 2048
#define NE      64
#define BM      128              // gemm tile: 128 tokens x 64 experts
#define KC      16               // k-chunk (floats)
#define KS      8                // split-K factor
#define KSEG    (D_MODEL / KS)   // 256 (acc chain length 256 = proven numerics)
#define NCHK    (KSEG / KC)      // 16 chunks per K-segment
#define FB_KC   32
#define FB_NCH  (D_MODEL / FB_KC)

// async 16B global->LDS DMA (LDS dest = wave-uniform base + lane*16)
__device__ __forceinline__ void async_copy16(const float* g, float* l) {
    __builtin_amdgcn_global_load_lds(
        (const __attribute__((address_space(1))) unsigned int*)g,
        (__attribute__((address_space(3))) unsigned int*)l, 16, 0, 0);
}

// ---------------- split-K GEMM: x[128 tok] x W[64 exp] over KSEG ------------
// A: global_load_lds DMA, 3-buffer, 2 chunks in flight, counted vmcnt(2).
//    vmcnt carries ONLY these DMAs (W is SMEM/lgkmcnt) -> in-order retirement
//    can't collapse the pipeline (round-4/5 flaw).
// W: wave-uniform SMEM loads into SGPRs (expert-per-wave assignment);
//    v_fmac takes the W value as its single SGPR operand.
// LDS slot(m,p) = m*4 + ((p + (m>>2))&3): DMA-source-swizzled so the
//    per-kq column reads spread uniformly across bank-quads.
__global__ __launch_bounds__(256) void router_gemm3(
    const float* __restrict__ x, const float* __restrict__ W,
    float* __restrict__ part, int ntiles)
{
    __shared__ __align__(16) float sX[3][BM * KC];   // 3 x 8KB

    const int t    = threadIdx.x;
    const int tile = blockIdx.x;
    const int ks   = blockIdx.y;
    const int m0   = tile * BM;
    const int k0   = ks * KSEG;
    const int l    = t & 63;                          // lane
    const int wv   = __builtin_amdgcn_readfirstlane(t >> 6);  // wave id (SGPR)

    // staging source: slot s holds x[m0 + (s>>2)][k.. + 4*(((s&3)-((s>>4)&3))&3)]
    const float* srcA = x + (size_t)(m0 + (t >> 2)) * D_MODEL + k0
                          + ((((t & 3) - ((t >> 4) & 3)) & 3) << 2);
    const float* Wseg = W + (size_t)(wv * 16) * D_MODEL + k0;  // uniform addr

    float acc[2][16] = {};           // tokens {l, l+64} x 16 experts

    // prologue: stage chunks 0 and 1 (each wave: 2 DMAs per chunk)
    async_copy16(srcA,                     &sX[0][wv * 256]);
    async_copy16(srcA + 64 * D_MODEL,      &sX[0][1024 + wv * 256]);
    async_copy16(srcA + KC,                &sX[1][wv * 256]);
    async_copy16(srcA + KC + 64 * D_MODEL, &sX[1][1024 + wv * 256]);

    int bufc = 0;
    for (int ch = 0; ch < NCHK; ++ch) {
        // in flight here: DMA pairs {ch, ch+1}; wait ch's pair, keep ch+1's
        if (ch + 1 < NCHK) { asm volatile("s_waitcnt vmcnt(2)" ::: "memory"); }
        else               { asm volatile("s_waitcnt vmcnt(0)" ::: "memory"); }
        __builtin_amdgcn_s_barrier();
        if (ch + 2 < NCHK) {         // stage ch+2 now: full 2-chunk flight
            const int bufs = (bufc == 0) ? 2 : bufc - 1;     // (bufc+2)%3
            const float* sg = srcA + (size_t)(ch + 2) * KC;
            async_copy16(sg,                &sX[bufs][wv * 256]);
            async_copy16(sg + 64 * D_MODEL, &sX[bufs][1024 + wv * 256]);
        }
        const float* lb = &sX[bufc][0];
        const float* wc = Wseg + ch * KC;                    // uniform
        #pragma unroll
        for (int kq = 0; kq < 4; ++kq) {
            const int qoff = ((kq + (l >> 2)) & 3) << 2;     // swizzled quad
            float4 avA = *(const float4*)&lb[(l << 4) + qoff];
            float4 avB = *(const float4*)&lb[(l << 4) + 1024 + qoff];
            #pragma unroll
            for (int j = 0; j < 16; ++j) {
                float4 wj = *(const float4*)&wc[(size_t)j * D_MODEL + kq * 4];
                acc[0][j] = fmaf(avA.x, wj.x, acc[0][j]);
                acc[0][j] = fmaf(avA.y, wj.y, acc[0][j]);
                acc[0][j] = fmaf(avA.z, wj.z, acc[0][j]);
                acc[0][j] = fmaf(avA.w, wj.w, acc[0][j]);
                acc[1][j] = fmaf(avB.x, wj.x, acc[1][j]);
                acc[1][j] = fmaf(avB.y, wj.y, acc[1][j]);
                acc[1][j] = fmaf(avB.z, wj.z, acc[1][j]);
                acc[1][j] = fmaf(avB.w, wj.w, acc[1][j]);
            }
        }
        bufc = (bufc == 2) ? 0 : bufc + 1;
    }

    float* dst = part + ((size_t)ks * ntiles + tile) * (BM * NE) + wv * 16;
    #pragma unroll
    for (int h = 0; h < 2; ++h) {
        float* drow = dst + (size_t)(h * 64 + l) * NE;
        #pragma unroll
        for (int g = 0; g < 4; ++g) {
            float4 v;
            v.x = acc[h][g * 4 + 0]; v.y = acc[h][g * 4 + 1];
            v.z = acc[h][g * 4 + 2]; v.w = acc[h][g * 4 + 3];
            *(float4*)&drow[g * 4] = v;
        }
    }
}

// ---------------- reduce 8 partials + fused stats (64 tokens/block) ---------
__global__ __launch_bounds__(256) void router_stats2(
    const float* __restrict__ part, float* __restrict__ out,
    float* __restrict__ ws_prob, float* __restrict__ ws_z,
    int* __restrict__ ws_cnt, int Ntok, int ntiles_g)
{
    __shared__ float sL[64][NE + 1];
    __shared__ float red4[64][4];
    __shared__ int   arg4[64][4];
    __shared__ float smax[64], sinv[64];
    __shared__ float spart[4][NE];
    __shared__ int   hist[NE];

    const int t = threadIdx.x, b = blockIdx.x, m0 = b * 64;
    const size_t ksstride = (size_t)ntiles_g * (BM * NE);
    const float* base = part + (size_t)(b >> 1) * (BM * NE)
                             + (size_t)(b & 1) * (64 * NE);

    #pragma unroll
    for (int r = 0; r < 4; ++r) {                    // sum 8 K-partials
        const int q = r * 256 + t;
        const float* p0 = base + (size_t)q * 4;
        float s0 = 0.f, s1 = 0.f, s2 = 0.f, s3 = 0.f;
        #pragma unroll
        for (int j = 0; j < 8; j += 2) {             // fixed order: deterministic
            float4 va = *(const float4*)(p0 + (size_t)j * ksstride);
            float4 vb = *(const float4*)(p0 + (size_t)(j + 1) * ksstride);
            s0 += va.x + vb.x; s1 += va.y + vb.y;
            s2 += va.z + vb.z; s3 += va.w + vb.w;
        }
        const int row = q >> 4, col = (q & 15) << 2;
        sL[row][col]     = s0; sL[row][col + 1] = s1;
        sL[row][col + 2] = s2; sL[row][col + 3] = s3;
    }
    if (t < NE) hist[t] = 0;
    __syncthreads();

    {   // per-quarter argmax (4 threads per token)
        const int m = t >> 2, qr = t & 3;
        float mx = -3.4e38f; int ag = 0;
        #pragma unroll
        for (int k = 0; k < 16; ++k) {
            const int e = qr * 16 + k;
            float v = sL[m][e];
            if (v > mx) { mx = v; ag = e; }
        }
        red4[m][qr] = mx; arg4[m][qr] = ag;
    }
    __syncthreads();
    if (t < 64) {                                    // combine: first-max kept
        const int m = t;
        float mx = red4[m][0]; int ag = arg4[m][0];
        #pragma unroll
        for (int qr = 1; qr < 4; ++qr)
            if (red4[m][qr] > mx) { mx = red4[m][qr]; ag = arg4[m][qr]; }
        smax[m] = mx;
        out[m0 + m] = (float)ag;                     // expert_index
        atomicAdd(&hist[ag], 1);
    }
    __syncthreads();
    {   // per-quarter expsum
        const int m = t >> 2, qr = t & 3;
        const float mx = smax[m];
        float s = 0.f;
        #pragma unroll
        for (int k = 0; k < 16; ++k) s += expf(sL[m][qr * 16 + k] - mx);
        red4[m][qr] = s;
    }
    __syncthreads();
    if (t < 64) {
        const int m = t;
        float s = ((red4[m][0] + red4[m][1]) + red4[m][2]) + red4[m][3];
        float inv = 1.f / s;
        sinv[m] = inv;
        out[Ntok + m0 + m] = inv;                    // expert_prob
        float lse = smax[m] + logf(s);
        float z = lse * lse;
        #pragma unroll
        for (int off = 32; off > 0; off >>= 1) z += __shfl_down(z, off, 64);
        if (t == 0) ws_z[b] = z;
    }
    __syncthreads();
    {   // probsum: wave mg covers 16 tokens, lane = expert
        const int e = t & 63, mg = t >> 6;
        float pa = 0.f;
        #pragma unroll
        for (int k = 0; k < 16; ++k) {
            const int m = mg * 16 + k;
            pa += expf(sL[m][e] - smax[m]) * sinv[m];
        }
        spart[mg][e] = pa;
    }
    __syncthreads();
    if (t < NE) {
        ws_prob[b * NE + t] = ((spart[0][t] + spart[1][t]) + spart[2][t]) + spart[3][t];
        ws_cnt[b * NE + t]  = hist[t];
    }
}

__global__ __launch_bounds__(64) void router_final_kernel(
    const float* __restrict__ ws_prob, const float* __restrict__ ws_z,
    const int* __restrict__ ws_cnt, float* __restrict__ out,
    int Ntok, int nblocks)
{
    const int e = threadIdx.x;
    float ps = 0.f; int c = 0;
    for (int blk = 0; blk < nblocks; ++blk) {        // fixed order: deterministic
        ps += ws_prob[blk * NE + e];
        c  += ws_cnt[blk * NE + e];
    }
    float z = 0.f;
    for (int blk = e; blk < nblocks; blk += 64) z += ws_z[blk];
    #pragma unroll
    for (int off = 32; off > 0; off >>= 1) z += __shfl_down(z, off, 64);

    float fN = (float)Ntok;
    float fp = ((float)c / fN) * (ps / fN);
    #pragma unroll
    for (int off = 32; off > 0; off >>= 1) fp += __shfl_down(fp, off, 64);

    out[2 * Ntok + e] = (float)c;
    if (e == 0) {
        int cap = (Ntok + NE - 1) / NE;
        if (cap < 4) cap = 4;
        float aux = 0.01f * (float)NE * fp + 1e-3f * (z / fN);
        out[2 * Ntok + NE]     = (float)cap;
        out[2 * Ntok + NE + 1] = aux;
    }
}

// ---------------- fallback (round-1 proven fused path) ----------------------
__global__ __launch_bounds__(256) void router_main_fb(
    const float* __restrict__ x, const float* __restrict__ W,
    float* __restrict__ out, float* __restrict__ ws_prob,
    float* __restrict__ ws_z, int* __restrict__ ws_cnt, int Ntok)
{
    __shared__ __align__(16) float sX[FB_KC][68];
    __shared__ __align__(16) float sW[FB_KC][68];
    __shared__ float sL[64][65];
    __shared__ float smax[64], sinv[64];
    __shared__ float spart[4][NE];
    __shared__ int   hist[NE];

    const int t = threadIdx.x, b = blockIdx.x, m0 = b * 64;
    const int mq = t & 15, nq = t >> 4;
    const int r1 = t >> 3, r2 = r1 + 32, c1 = (t & 7) << 2;
    const float* xp1 = x + (size_t)(m0 + r1) * D_MODEL + c1;
    const float* xp2 = x + (size_t)(m0 + r2) * D_MODEL + c1;
    const float* wp1 = W + (size_t)r1 * D_MODEL + c1;
    const float* wp2 = W + (size_t)r2 * D_MODEL + c1;
    float4 ax1 = *(const float4*)xp1, ax2 = *(const float4*)xp2;
    float4 aw1 = *(const float4*)wp1, aw2 = *(const float4*)wp2;
    float a1[4][4] = {}, a2[4][4] = {};
    for (int ch = 0; ch < FB_NCH; ++ch) {
        __syncthreads();
        sX[c1+0][r1] = ax1.x; sX[c1+1][r1] = ax1.y; sX[c1+2][r1] = ax1.z; sX[c1+3][r1] = ax1.w;
        sX[c1+0][r2] = ax2.x; sX[c1+1][r2] = ax2.y; sX[c1+2][r2] = ax2.z; sX[c1+3][r2] = ax2.w;
        sW[c1+0][r1] = aw1.x; sW[c1+1][r1] = aw1.y; sW[c1+2][r1] = aw1.z; sW[c1+3][r1] = aw1.w;
        sW[c1+0][r2] = aw2.x; sW[c1+1][r2] = aw2.y; sW[c1+2][r2] = aw2.z; sW[c1+3][r2] = aw2.w;
        __syncthreads();
        if (ch + 1 < FB_NCH) {
            xp1 += FB_KC; xp2 += FB_KC; wp1 += FB_KC; wp2 += FB_KC;
            ax1 = *(const float4*)xp1; ax2 = *(const float4*)xp2;
            aw1 = *(const float4*)wp1; aw2 = *(const float4*)wp2;
        }
        #pragma unroll
        for (int k = 0; k < FB_KC; ++k) {
            float4 xa = *(const float4*)&sX[k][mq << 2];
            float4 wb = *(const float4*)&sW[k][nq << 2];
            float (*A)[4] = (k < FB_KC / 2) ? a1 : a2;
            A[0][0] = fmaf(xa.x, wb.x, A[0][0]); A[0][1] = fmaf(xa.x, wb.y, A[0][1]);
            A[0][2] = fmaf(xa.x, wb.z, A[0][2]); A[0][3] = fmaf(xa.x, wb.w, A[0][3]);
            A[1][0] = fmaf(xa.y, wb.x, A[1][0]); A[1][1] = fmaf(xa.y, wb.y, A[1][1]);
            A[1][2] = fmaf(xa.y, wb.z, A[1][2]); A[1][3] = fmaf(xa.y, wb.w, A[1][3]);
            A[2][0] = fmaf(xa.z, wb.x, A[2][0]); A[2][1] = fmaf(xa.z, wb.y, A[2][1]);
            A[2][2] = fmaf(xa.z, wb.z, A[2][2]); A[2][3] = fmaf(xa.z, wb.w, A[2][3]);
            A[3][0] = fmaf(xa.w, wb.x, A[3][0]); A[3][1] = fmaf(xa.w, wb.y, A[3][1]);
            A[3][2] = fmaf(xa.w, wb.z, A[3][2]); A[3][3] = fmaf(xa.w, wb.w, A[3][3]);
        }
    }
    #pragma unroll
    for (int i = 0; i < 4; ++i)
        #pragma unroll
        for (int j = 0; j < 4; ++j)
            sL[(mq << 2) + i][(nq << 2) + j] = a1[i][j] + a2[i][j];
    if (t < NE) hist[t] = 0;
    __syncthreads();
    if (t < 64) {
        const int m = t;
        float mx = sL[m][0]; int arg = 0;
        for (int e = 1; e < NE; ++e) { float v = sL[m][e]; if (v > mx) { mx = v; arg = e; } }
        float s = 0.f;
        for (int e = 0; e < NE; ++e) s += expf(sL[m][e] - mx);
        float inv = 1.f / s;
        out[m0 + m] = (float)arg; out[Ntok + m0 + m] = inv;
        smax[m] = mx; sinv[m] = inv;
        atomicAdd(&hist[arg], 1);
        float lse = mx + logf(s); float z = lse * lse;
        for (int off = 32; off > 0; off >>= 1) z += __shfl_down(z, off, 64);
        if (t == 0) ws_z[b] = z;
    }
    __syncthreads();
    {
        const int e = t & 63, mg = t >> 6;
        float pa = 0.f;
        for (int m = mg * 16; m < mg * 16 + 16; ++m) pa += expf(sL[m][e] - smax[m]) * sinv[m];
        spart[mg][e] = pa;
    }
    __syncthreads();
    if (t < NE) {
        ws_prob[b * NE + t] = spart[0][t] + spart[1][t] + spart[2][t] + spart[3][t];
        ws_cnt[b * NE + t]  = hist[t];
    }
}

extern "C" void kernel_launch(void* const* d_in, const int* in_sizes, int n_in,
                              void* d_out, int out_size, void* d_ws, size_t ws_size,
                              hipStream_t stream)
{
    const float* x = (const float*)d_in[0];
    const float* W = (const float*)d_in[1];
    float* out = (float*)d_out;

    const int Ntok = in_sizes[0] / D_MODEL;          // 16384

    const int ntiles_g = Ntok / BM;                  // 128
    const int nstat    = Ntok / 64;                  // 256
    const size_t part_elems = (size_t)KS * ntiles_g * BM * NE;   // 8.39M floats
    const size_t need = (part_elems + (size_t)nstat * NE + nstat) * 4
                      + (size_t)nstat * NE * 4 + 1024;

    if ((Ntok % BM) == 0 && ws_size >= need) {
        float* ws_part = (float*)d_ws;
        float* ws_prob = ws_part + part_elems;
        float* ws_z    = ws_prob + (size_t)nstat * NE;
        int*   ws_cnt  = (int*)(ws_z + nstat);

        dim3 grid(ntiles_g, KS);
        router_gemm3<<<grid, 256, 0, stream>>>(x, W, ws_part, ntiles_g);
        router_stats2<<<nstat, 256, 0, stream>>>(ws_part, out, ws_prob, ws_z, ws_cnt, Ntok, ntiles_g);
        router_final_kernel<<<1, 64, 0, stream>>>(ws_prob, ws_z, ws_cnt, out, Ntok, nstat);
    } else {
        const int nb = Ntok / 64;
        float* ws_prob = (float*)d_ws;
        float* ws_z    = ws_prob + (size_t)nb * NE;
        int*   ws_cnt  = (int*)(ws_z + nb);
        router_main_fb<<<nb, 256, 0, stream>>>(x, W, out, ws_prob, ws_z, ws_cnt, Ntok);
        router_final_kernel<<<1, 64, 0, stream>>>(ws_prob, ws_z, ws_cnt, out, Ntok, nb);
    }
}